// Round 4
// baseline (1671.003 us; speedup 1.0000x reference)
//
#include <hip/hip_runtime.h>

#define BN_EPS 1e-5f

// ---------------- degree / dinv ----------------

__global__ __launch_bounds__(256) void k_deg_count(const int* __restrict__ dst, int* deg, int e) {
    int i = blockIdx.x * 256 + threadIdx.x;
    if (i < e) atomicAdd(&deg[dst[i]], 1);
}

__global__ __launch_bounds__(256) void k_dinv(const int* __restrict__ deg, float* __restrict__ dinv, int n) {
    int i = blockIdx.x * 256 + threadIdx.x;
    if (i < n) dinv[i] = rsqrtf((float)deg[i] + 1.0f);   // +1 = self-loop
}

// ---------------- exclusive scan (CSR offsets) ----------------

__global__ __launch_bounds__(256) void k_scan1(const int* __restrict__ deg, int* __restrict__ off,
                                               int* __restrict__ bsum, int n) {
    __shared__ int sh[256];
    int i = blockIdx.x * 256 + threadIdx.x;
    int v = (i < n) ? deg[i] : 0;
    sh[threadIdx.x] = v;
    __syncthreads();
    #pragma unroll
    for (int d = 1; d < 256; d <<= 1) {
        int t = (threadIdx.x >= d) ? sh[threadIdx.x - d] : 0;
        __syncthreads();
        sh[threadIdx.x] += t;
        __syncthreads();
    }
    if (i < n) off[i] = sh[threadIdx.x] - v;
    if (threadIdx.x == 255) bsum[blockIdx.x] = sh[255];
}

__global__ __launch_bounds__(512) void k_scan2(int* bsum, int nb) {
    __shared__ int sh[512];
    int v = (threadIdx.x < nb) ? bsum[threadIdx.x] : 0;
    sh[threadIdx.x] = v;
    __syncthreads();
    #pragma unroll
    for (int d = 1; d < 512; d <<= 1) {
        int t = (threadIdx.x >= d) ? sh[threadIdx.x - d] : 0;
        __syncthreads();
        sh[threadIdx.x] += t;
        __syncthreads();
    }
    if (threadIdx.x < nb) bsum[threadIdx.x] = sh[threadIdx.x] - v;
}

__global__ __launch_bounds__(256) void k_scan3(int* __restrict__ off, const int* __restrict__ bsum,
                                               int* __restrict__ cnt, int n, int e) {
    int i = blockIdx.x * 256 + threadIdx.x;
    if (i < n) { off[i] += bsum[blockIdx.x]; cnt[i] = 0; }
    if (i == 0) off[n] = e;
}

__global__ __launch_bounds__(256) void k_fill(const int* __restrict__ src, const int* __restrict__ dst,
                                              const int* __restrict__ off, int* __restrict__ cnt,
                                              int* __restrict__ esrc, int e) {
    int i = blockIdx.x * 256 + threadIdx.x;
    if (i < e) {
        int d = dst[i];
        int slot = off[d] + atomicAdd(&cnt[d], 1);
        esrc[slot] = src[i];
    }
}

// ---------------- dense linear ----------------
// block 256 = 4 waves; 32-row tile staged in LDS (BN+relu applied during staging).
// Wave lane = output col (FOUT=64) or (col, row-subset) for FOUT=16. Weights held in
// registers as K-chunks of <=64 (no spill: ~90 VGPR total). X read via broadcast float4.

template<int FIN, int FOUT, bool RELU, bool BIAS, bool BNIN, bool DSCALE>
__global__ __launch_bounds__(256) void k_linear(const float* __restrict__ X, const float* __restrict__ W,
                                                const float* __restrict__ bias, float* __restrict__ Y,
                                                const float* __restrict__ S, const float* __restrict__ bng,
                                                const float* __restrict__ bnb, const float* __restrict__ dinv,
                                                float inv_n, int n) {
    constexpr int RB  = 32;                    // rows per block-iter
    constexpr int RW  = RB / 4;                // rows per wave = 8
    constexpr int CS  = 64 / FOUT;             // col-sets per wave (1 or 4)
    constexpr int RR  = RW / CS;               // rows per lane (8 or 2)
    constexpr int WCH = (FIN > 64) ? 64 : FIN; // K-chunk held in VGPRs
    constexpr int LDF = FIN + 4;
    __shared__ float Xs[RB][LDF];
    __shared__ float scs[BNIN ? FIN : 4], sfs[BNIN ? FIN : 4];

    const int wv   = threadIdx.x >> 6;
    const int lane = threadIdx.x & 63;
    const int col  = lane % FOUT;
    const int rsub = lane / FOUT;

    if (BNIN) {
        for (int c = threadIdx.x; c < FIN; c += 256) {
            float mu = S[c] * inv_n;
            float var = S[FIN + c] * inv_n - mu * mu;
            float is = rsqrtf(var + BN_EPS) * bng[c];
            scs[c] = is;
            sfs[c] = bnb[c] - mu * is;
        }
        __syncthreads();
    }

    // persistent weight registers when FIN fits in one chunk
    float WregP[WCH];
    if (FIN <= WCH) {
        #pragma unroll
        for (int j = 0; j < WCH; ++j) WregP[j] = W[j * FOUT + col];
    }
    const float bcol = BIAS ? bias[col] : 0.0f;

    for (int r0 = blockIdx.x * RB; r0 < n; r0 += gridDim.x * RB) {
        __syncthreads();
        // stage 32 x FIN tile (coalesced float4 loads, BN+relu applied here)
        for (int idx = threadIdx.x; idx < RB * (FIN / 4); idx += 256) {
            int rr = idx / (FIN / 4), k4 = idx % (FIN / 4);
            int row = r0 + rr;
            float4 v = make_float4(0.f, 0.f, 0.f, 0.f);
            if (row < n) v = *(const float4*)(X + (size_t)row * FIN + 4 * k4);
            if (BNIN) {
                v.x = fmaxf(fmaf(v.x, scs[4*k4+0], sfs[4*k4+0]), 0.f);
                v.y = fmaxf(fmaf(v.y, scs[4*k4+1], sfs[4*k4+1]), 0.f);
                v.z = fmaxf(fmaf(v.z, scs[4*k4+2], sfs[4*k4+2]), 0.f);
                v.w = fmaxf(fmaf(v.w, scs[4*k4+3], sfs[4*k4+3]), 0.f);
            }
            *(float4*)(&Xs[rr][4 * k4]) = v;
        }
        __syncthreads();

        float acc[RR];
        #pragma unroll
        for (int q = 0; q < RR; ++q) acc[q] = bcol;

        #pragma unroll
        for (int kc = 0; kc < FIN; kc += WCH) {
            if (FIN <= WCH) {
                #pragma unroll
                for (int q = 0; q < RR; ++q) {
                    int rr = wv * RW + rsub * RR + q;
                    #pragma unroll
                    for (int k4 = 0; k4 < WCH / 4; ++k4) {
                        float4 xv = *(const float4*)(&Xs[rr][4 * k4]);
                        acc[q] = fmaf(xv.x, WregP[4*k4+0], acc[q]);
                        acc[q] = fmaf(xv.y, WregP[4*k4+1], acc[q]);
                        acc[q] = fmaf(xv.z, WregP[4*k4+2], acc[q]);
                        acc[q] = fmaf(xv.w, WregP[4*k4+3], acc[q]);
                    }
                }
            } else {
                float Wreg[WCH];
                #pragma unroll
                for (int j = 0; j < WCH; ++j) Wreg[j] = W[(kc + j) * FOUT + col];
                #pragma unroll
                for (int q = 0; q < RR; ++q) {
                    int rr = wv * RW + rsub * RR + q;
                    #pragma unroll
                    for (int k4 = 0; k4 < WCH / 4; ++k4) {
                        float4 xv = *(const float4*)(&Xs[rr][kc + 4 * k4]);
                        acc[q] = fmaf(xv.x, Wreg[4*k4+0], acc[q]);
                        acc[q] = fmaf(xv.y, Wreg[4*k4+1], acc[q]);
                        acc[q] = fmaf(xv.z, Wreg[4*k4+2], acc[q]);
                        acc[q] = fmaf(xv.w, Wreg[4*k4+3], acc[q]);
                    }
                }
            }
        }

        #pragma unroll
        for (int q = 0; q < RR; ++q) {
            int row = r0 + wv * RW + rsub * RR + q;
            if (row < n) {
                float v = acc[q];
                if (RELU) v = fmaxf(v, 0.f);
                if (DSCALE) v *= dinv[row];
                Y[(size_t)row * FOUT + col] = v;
            }
        }
    }
}

// ---------------- GCN accumulate (CSR gather), T pre-scaled by dinv[row] ----------------
// Z[d,:] = dinv[d] * ( T[d,:] + sum_{s in N(d)} T[s,:] ) + bias ; + BN partial stats

__global__ __launch_bounds__(256) void k_accum64(const float* __restrict__ T, const int* __restrict__ esrc,
                                                 const int* __restrict__ off, const float* __restrict__ dinv,
                                                 const float* __restrict__ bias, float* __restrict__ Z,
                                                 float* __restrict__ S, int n) {
    const int lane = threadIdx.x & 63;
    const int wid = threadIdx.x >> 6;
    float s1 = 0.f, s2 = 0.f;
    const float bcol = bias[lane];
    for (int d = blockIdx.x * 4 + wid; d < n; d += gridDim.x * 4) {
        int o0 = off[d], o1 = off[d + 1];
        float dv = dinv[d];
        float acc = T[(size_t)d * 64 + lane];
        int o = o0;
        for (; o + 8 <= o1; o += 8) {
            int sa = esrc[o+0], sb = esrc[o+1], sc = esrc[o+2], sd = esrc[o+3];
            int se = esrc[o+4], sf = esrc[o+5], sg = esrc[o+6], sh = esrc[o+7];
            float va = T[(size_t)sa*64+lane], vb = T[(size_t)sb*64+lane];
            float vc = T[(size_t)sc*64+lane], vd = T[(size_t)sd*64+lane];
            float ve = T[(size_t)se*64+lane], vf = T[(size_t)sf*64+lane];
            float vg = T[(size_t)sg*64+lane], vh = T[(size_t)sh*64+lane];
            acc += ((va + vb) + (vc + vd)) + ((ve + vf) + (vg + vh));
        }
        for (; o + 2 <= o1; o += 2) {
            int sa = esrc[o], sb = esrc[o+1];
            acc += T[(size_t)sa*64+lane] + T[(size_t)sb*64+lane];
        }
        if (o < o1) acc += T[(size_t)esrc[o]*64+lane];
        float z = fmaf(acc, dv, bcol);
        Z[(size_t)d * 64 + lane] = z;
        s1 += z; s2 += z * z;
    }
    __shared__ float sh1[256], sh2[256];
    sh1[threadIdx.x] = s1;
    sh2[threadIdx.x] = s2;
    __syncthreads();
    if (wid == 0) {
        #pragma unroll
        for (int w = 1; w < 4; ++w) { s1 += sh1[w * 64 + lane]; s2 += sh2[w * 64 + lane]; }
        atomicAdd(&S[lane], s1);
        atomicAdd(&S[64 + lane], s2);
    }
}

// F == 16: one node per wave, 4 edges per iteration (lane = 4 edge-slots x 16 cols)
__global__ __launch_bounds__(256) void k_accum16(const float* __restrict__ T, const int* __restrict__ esrc,
                                                 const int* __restrict__ off, const float* __restrict__ dinv,
                                                 const float* __restrict__ bias, float* __restrict__ Z,
                                                 float* __restrict__ S, int n) {
    const int lane = threadIdx.x & 63;
    const int wid = threadIdx.x >> 6;
    const int col = lane & 15;
    const int es  = lane >> 4;
    float s1 = 0.f, s2 = 0.f;
    const float bcol = bias[col];
    for (int d = blockIdx.x * 4 + wid; d < n; d += gridDim.x * 4) {
        int o0 = off[d], o1 = off[d + 1];
        float dv = dinv[d];
        float part = 0.f;
        for (int base = o0; base < o1; base += 4) {
            int oo = base + es;
            if (oo < o1) part += T[(size_t)esrc[oo] * 16 + col];
        }
        part += __shfl_xor(part, 16);
        part += __shfl_xor(part, 32);
        float acc = T[(size_t)d * 16 + col] + part;
        float z = fmaf(acc, dv, bcol);
        if (es == 0) {
            Z[(size_t)d * 16 + col] = z;
            s1 += z; s2 += z * z;
        }
    }
    __shared__ float sh1[256], sh2[256];
    sh1[threadIdx.x] = (es == 0) ? s1 : 0.f;
    sh2[threadIdx.x] = (es == 0) ? s2 : 0.f;
    __syncthreads();
    if (threadIdx.x < 16) {
        s1 = sh1[col]; s2 = sh2[col];
        #pragma unroll
        for (int r = 1; r < 16; ++r) { s1 += sh1[r * 16 + col]; s2 += sh2[r * 16 + col]; }
        atomicAdd(&S[col], s1);
        atomicAdd(&S[16 + col], s2);
    }
}

// ---------------- fc2 + log_softmax (fused BN+relu input) ----------------

__global__ __launch_bounds__(256) void k_fc2_lsm(const float* __restrict__ Hin, const float* __restrict__ W,
                                                 const float* __restrict__ bias, const float* __restrict__ S,
                                                 const float* __restrict__ bng, const float* __restrict__ bnb,
                                                 float inv_n, float* __restrict__ out, int n) {
    __shared__ float Ws[256];
    __shared__ float bs[16], sc[16], sf[16];
    Ws[threadIdx.x] = W[threadIdx.x];
    if (threadIdx.x < 16) {
        int c = threadIdx.x;
        bs[c] = bias[c];
        float mu = S[c] * inv_n;
        float var = S[16 + c] * inv_n - mu * mu;
        float is = rsqrtf(var + BN_EPS) * bng[c];
        sc[c] = is;
        sf[c] = bnb[c] - mu * is;
    }
    __syncthreads();
    for (int row = blockIdx.x * 256 + threadIdx.x; row < n; row += gridDim.x * 256) {
        float h[16];
        const float4* hp = (const float4*)(Hin + (size_t)row * 16);
        #pragma unroll
        for (int q = 0; q < 4; ++q) {
            float4 h4 = hp[q];
            h[q*4+0] = h4.x; h[q*4+1] = h4.y; h[q*4+2] = h4.z; h[q*4+3] = h4.w;
        }
        #pragma unroll
        for (int k = 0; k < 16; ++k) h[k] = fmaxf(fmaf(h[k], sc[k], sf[k]), 0.0f);
        float o[16];
        #pragma unroll
        for (int c = 0; c < 16; ++c) {
            float acc = bs[c];
            #pragma unroll
            for (int k = 0; k < 16; ++k) acc += h[k] * Ws[k * 16 + c];
            o[c] = acc;
        }
        float m = o[0];
        #pragma unroll
        for (int c = 1; c < 16; ++c) m = fmaxf(m, o[c]);
        float ssum = 0.f;
        #pragma unroll
        for (int c = 0; c < 16; ++c) ssum += expf(o[c] - m);
        float lse = m + logf(ssum);
        float4* op = (float4*)(out + (size_t)row * 16);
        #pragma unroll
        for (int q = 0; q < 4; ++q) {
            float4 w4;
            w4.x = o[q*4+0] - lse; w4.y = o[q*4+1] - lse;
            w4.z = o[q*4+2] - lse; w4.w = o[q*4+3] - lse;
            op[q] = w4;
        }
    }
}

// ---------------- launch ----------------

extern "C" void kernel_launch(void* const* d_in, const int* in_sizes, int n_in,
                              void* d_out, int out_size, void* d_ws, size_t ws_size,
                              hipStream_t stream) {
    const float* x      = (const float*)d_in[0];
    const int*   ei     = (const int*)d_in[1];
    const float* fc1_w  = (const float*)d_in[2];
    const float* fc1_b  = (const float*)d_in[3];
    const float* conv_w[3] = { (const float*)d_in[4],  (const float*)d_in[8],  (const float*)d_in[12] };
    const float* conv_b[3] = { (const float*)d_in[5],  (const float*)d_in[9],  (const float*)d_in[13] };
    const float* bn_g[3]   = { (const float*)d_in[6],  (const float*)d_in[10], (const float*)d_in[14] };
    const float* bn_b[3]   = { (const float*)d_in[7],  (const float*)d_in[11], (const float*)d_in[15] };
    const float* fc2_w  = (const float*)d_in[16];
    const float* fc2_b  = (const float*)d_in[17];

    const int n = in_sizes[0] / 128;
    const int e = in_sizes[1] / 2;
    const int* src = ei;
    const int* dst = ei + e;
    const float inv_n = 1.0f / (float)n;

    float* A    = (float*)d_ws;            // n*64
    float* B    = A + (size_t)n * 64;      // n*64
    float* dinv = B + (size_t)n * 64;      // n
    int*   deg  = (int*)(dinv + n);        // n  (doubles as cnt)
    int*   off  = deg + n;                 // n+1
    int*   esrc = off + n + 1;             // e
    float* stats = (float*)(esrc + e);     // 3*128
    int*   bsum = (int*)(stats + 384);     // <=512

    const int gN  = (n + 255) / 256;
    const int gE  = (e + 255) / 256;
    const int gLin = 2048;
    const int gAcc = 2048;

    float* st[3] = { stats, stats + 128, stats + 256 };

    // CSR build (shared by all 3 conv layers)
    hipMemsetAsync(deg, 0, (size_t)n * sizeof(int), stream);
    hipMemsetAsync(stats, 0, 384 * sizeof(float), stream);
    k_deg_count<<<gE, 256, 0, stream>>>(dst, deg, e);
    k_dinv<<<gN, 256, 0, stream>>>(deg, dinv, n);
    k_scan1<<<gN, 256, 0, stream>>>(deg, off, bsum, n);
    k_scan2<<<1, 512, 0, stream>>>(bsum, gN);
    k_scan3<<<gN, 256, 0, stream>>>(off, bsum, deg /*cnt*/, n, e);
    k_fill<<<gE, 256, 0, stream>>>(src, dst, off, deg /*cnt*/, esrc, e);

    // fc1 + relu : A = relu(x @ W1 + b1)
    k_linear<128, 64, true, true, false, false><<<gLin, 256, 0, stream>>>(
        x, fc1_w, fc1_b, A, nullptr, nullptr, nullptr, nullptr, 0.f, n);

    // conv0: B = (A @ W0) * dinv[row] ; A = gcn(B) (+bias, +stats0)
    k_linear<64, 64, false, false, false, true><<<gLin, 256, 0, stream>>>(
        A, conv_w[0], nullptr, B, nullptr, nullptr, nullptr, dinv, 0.f, n);
    k_accum64<<<gAcc, 256, 0, stream>>>(B, esrc, off, dinv, conv_b[0], A, st[0], n);

    // conv1: B = (bnrelu(A) @ W1) * dinv[row] ; A = gcn(B)
    k_linear<64, 64, false, false, true, true><<<gLin, 256, 0, stream>>>(
        A, conv_w[1], nullptr, B, st[0], bn_g[0], bn_b[0], dinv, inv_n, n);
    k_accum64<<<gAcc, 256, 0, stream>>>(B, esrc, off, dinv, conv_b[1], A, st[1], n);

    // conv2: B = (bnrelu(A) @ W2) * dinv[row] (64->16) ; A = gcn(B)
    k_linear<64, 16, false, false, true, true><<<gLin, 256, 0, stream>>>(
        A, conv_w[2], nullptr, B, st[1], bn_g[1], bn_b[1], dinv, inv_n, n);
    k_accum16<<<gAcc, 256, 0, stream>>>(B, esrc, off, dinv, conv_b[2], A, st[2], n);

    // fc2 + log_softmax (bn+relu fused on input) -> d_out
    k_fc2_lsm<<<gLin, 256, 0, stream>>>(A, fc2_w, fc2_b, st[2], bn_g[2], bn_b[2], inv_n, (float*)d_out, n);
}

// Round 5
// 546.346 us; speedup vs baseline: 3.0585x; 3.0585x over previous
//
#include <hip/hip_runtime.h>

#define BN_EPS 1e-5f

__device__ __forceinline__ void fma4(float4& a, float s, const float4& w) {
    a.x = fmaf(s, w.x, a.x); a.y = fmaf(s, w.y, a.y);
    a.z = fmaf(s, w.z, a.z); a.w = fmaf(s, w.w, a.w);
}

// ---------------- degree / dinv ----------------

__global__ __launch_bounds__(256) void k_deg_count(const int* __restrict__ dst, int* deg, int e) {
    int i = blockIdx.x * 256 + threadIdx.x;
    if (i < e) atomicAdd(&deg[dst[i]], 1);
}

__global__ __launch_bounds__(256) void k_dinv(const int* __restrict__ deg, float* __restrict__ dinv, int n) {
    int i = blockIdx.x * 256 + threadIdx.x;
    if (i < n) dinv[i] = rsqrtf((float)deg[i] + 1.0f);   // +1 = self-loop
}

// ---------------- exclusive scan (CSR offsets) ----------------

__global__ __launch_bounds__(256) void k_scan1(const int* __restrict__ deg, int* __restrict__ off,
                                               int* __restrict__ bsum, int n) {
    __shared__ int sh[256];
    int i = blockIdx.x * 256 + threadIdx.x;
    int v = (i < n) ? deg[i] : 0;
    sh[threadIdx.x] = v;
    __syncthreads();
    #pragma unroll
    for (int d = 1; d < 256; d <<= 1) {
        int t = (threadIdx.x >= d) ? sh[threadIdx.x - d] : 0;
        __syncthreads();
        sh[threadIdx.x] += t;
        __syncthreads();
    }
    if (i < n) off[i] = sh[threadIdx.x] - v;
    if (threadIdx.x == 255) bsum[blockIdx.x] = sh[255];
}

__global__ __launch_bounds__(512) void k_scan2(int* bsum, int nb) {
    __shared__ int sh[512];
    int v = (threadIdx.x < nb) ? bsum[threadIdx.x] : 0;
    sh[threadIdx.x] = v;
    __syncthreads();
    #pragma unroll
    for (int d = 1; d < 512; d <<= 1) {
        int t = (threadIdx.x >= d) ? sh[threadIdx.x - d] : 0;
        __syncthreads();
        sh[threadIdx.x] += t;
        __syncthreads();
    }
    if (threadIdx.x < nb) bsum[threadIdx.x] = sh[threadIdx.x] - v;
}

__global__ __launch_bounds__(256) void k_scan3(int* __restrict__ off, const int* __restrict__ bsum,
                                               int* __restrict__ cnt, int n, int e) {
    int i = blockIdx.x * 256 + threadIdx.x;
    if (i < n) { off[i] += bsum[blockIdx.x]; cnt[i] = 0; }
    if (i == 0) off[n] = e;
}

__global__ __launch_bounds__(256) void k_fill(const int* __restrict__ src, const int* __restrict__ dst,
                                              const int* __restrict__ off, int* __restrict__ cnt,
                                              int* __restrict__ esrc, int e) {
    int i = blockIdx.x * 256 + threadIdx.x;
    if (i < e) {
        int d = dst[i];
        int slot = off[d] + atomicAdd(&cnt[d], 1);
        esrc[slot] = src[i];
    }
}

// ---------------- dense linear: X-tile and W-tile both in LDS, RQx4 register sub-tile ----
// 256 threads = TX col-groups (4 cols each) x TY row-groups (RQ rows each).
// Per k4: 4 x b128 (W rows) + RQ x b128 (X rows, wave-broadcast) -> 16*RQ FMAs.

template<int FIN, int FOUT, bool RELU, bool BIAS, bool BNIN, bool DSCALE>
__global__ __launch_bounds__(256) void k_linear(const float* __restrict__ X, const float* __restrict__ W,
                                                const float* __restrict__ bias, float* __restrict__ Y,
                                                const float* __restrict__ S, const float* __restrict__ bng,
                                                const float* __restrict__ bnb, const float* __restrict__ dinv,
                                                float inv_n, int n) {
    constexpr int KC = 64;                        // K-chunk (FIN is 64 or 128)
    constexpr int TX = FOUT / 4;                  // col-groups (16 or 4)
    constexpr int TY = 256 / TX;                  // row-groups (16 or 64)
    constexpr int RQ = (FOUT == 64) ? 4 : 2;      // rows per thread
    constexpr int TILE_R = TY * RQ;               // 64 or 128
    constexpr int LDX = KC + 4;
    constexpr int LDW = FOUT + 4;
    __shared__ float Xs[TILE_R][LDX];
    __shared__ float Ws[KC][LDW];
    __shared__ float scs[BNIN ? FIN : 4], sfs[BNIN ? FIN : 4];

    const int tx = threadIdx.x % TX;
    const int ty = threadIdx.x / TX;

    if (BNIN) {
        for (int c = threadIdx.x; c < FIN; c += 256) {
            float mu = S[c] * inv_n;
            float var = S[FIN + c] * inv_n - mu * mu;
            float is = rsqrtf(var + BN_EPS) * bng[c];
            scs[c] = is;
            sfs[c] = bnb[c] - mu * is;
        }
        __syncthreads();
    }

    float4 bb = make_float4(0.f, 0.f, 0.f, 0.f);
    if (BIAS) bb = *(const float4*)(bias + tx * 4);

    for (int r0 = blockIdx.x * TILE_R; r0 < n; r0 += gridDim.x * TILE_R) {
        float4 acc[RQ];
        #pragma unroll
        for (int q = 0; q < RQ; ++q) acc[q] = bb;

        for (int kc = 0; kc < FIN; kc += KC) {
            __syncthreads();
            // stage X chunk (BN+relu fused)
            for (int idx = threadIdx.x; idx < TILE_R * (KC / 4); idx += 256) {
                int rr = idx / (KC / 4), k4 = idx % (KC / 4);
                int row = r0 + rr;
                float4 v = make_float4(0.f, 0.f, 0.f, 0.f);
                if (row < n) v = *(const float4*)(X + (size_t)row * FIN + kc + 4 * k4);
                if (BNIN) {
                    int c = kc + 4 * k4;
                    v.x = fmaxf(fmaf(v.x, scs[c+0], sfs[c+0]), 0.f);
                    v.y = fmaxf(fmaf(v.y, scs[c+1], sfs[c+1]), 0.f);
                    v.z = fmaxf(fmaf(v.z, scs[c+2], sfs[c+2]), 0.f);
                    v.w = fmaxf(fmaf(v.w, scs[c+3], sfs[c+3]), 0.f);
                }
                *(float4*)(&Xs[rr][4 * k4]) = v;
            }
            // stage W chunk
            for (int idx = threadIdx.x; idx < KC * (FOUT / 4); idx += 256) {
                int kk = idx / (FOUT / 4), c4 = idx % (FOUT / 4);
                *(float4*)(&Ws[kk][4 * c4]) = *(const float4*)(W + (size_t)(kc + kk) * FOUT + 4 * c4);
            }
            __syncthreads();

            #pragma unroll 4
            for (int k4 = 0; k4 < KC / 4; ++k4) {
                float4 w0 = *(const float4*)(&Ws[4*k4+0][tx*4]);
                float4 w1 = *(const float4*)(&Ws[4*k4+1][tx*4]);
                float4 w2 = *(const float4*)(&Ws[4*k4+2][tx*4]);
                float4 w3 = *(const float4*)(&Ws[4*k4+3][tx*4]);
                #pragma unroll
                for (int q = 0; q < RQ; ++q) {
                    float4 xv = *(const float4*)(&Xs[ty*RQ+q][4*k4]);
                    fma4(acc[q], xv.x, w0);
                    fma4(acc[q], xv.y, w1);
                    fma4(acc[q], xv.z, w2);
                    fma4(acc[q], xv.w, w3);
                }
            }
        }

        #pragma unroll
        for (int q = 0; q < RQ; ++q) {
            int row = r0 + ty * RQ + q;
            if (row < n) {
                float4 v = acc[q];
                if (RELU) {
                    v.x = fmaxf(v.x, 0.f); v.y = fmaxf(v.y, 0.f);
                    v.z = fmaxf(v.z, 0.f); v.w = fmaxf(v.w, 0.f);
                }
                if (DSCALE) {
                    float dv = dinv[row];
                    v.x *= dv; v.y *= dv; v.z *= dv; v.w *= dv;
                }
                *(float4*)(Y + (size_t)row * FOUT + tx * 4) = v;
            }
        }
    }
}

// ---------------- GCN accumulate (CSR gather), T pre-scaled by dinv[row] ----------------
// Z[d,:] = dinv[d] * ( T[d,:] + sum_{s in N(d)} T[s,:] ) + bias ; + BN partial stats

__global__ __launch_bounds__(256) void k_accum64(const float* __restrict__ T, const int* __restrict__ esrc,
                                                 const int* __restrict__ off, const float* __restrict__ dinv,
                                                 const float* __restrict__ bias, float* __restrict__ Z,
                                                 float* __restrict__ S, int n) {
    const int lane = threadIdx.x & 63;
    const int wid = threadIdx.x >> 6;
    float s1 = 0.f, s2 = 0.f;
    const float bcol = bias[lane];
    for (int d = blockIdx.x * 4 + wid; d < n; d += gridDim.x * 4) {
        int o0 = off[d], o1 = off[d + 1];
        float dv = dinv[d];
        float acc = T[(size_t)d * 64 + lane];
        int o = o0;
        for (; o + 8 <= o1; o += 8) {
            int sa = esrc[o+0], sb = esrc[o+1], sc = esrc[o+2], sd = esrc[o+3];
            int se = esrc[o+4], sf = esrc[o+5], sg = esrc[o+6], sh = esrc[o+7];
            float va = T[(size_t)sa*64+lane], vb = T[(size_t)sb*64+lane];
            float vc = T[(size_t)sc*64+lane], vd = T[(size_t)sd*64+lane];
            float ve = T[(size_t)se*64+lane], vf = T[(size_t)sf*64+lane];
            float vg = T[(size_t)sg*64+lane], vh = T[(size_t)sh*64+lane];
            acc += ((va + vb) + (vc + vd)) + ((ve + vf) + (vg + vh));
        }
        for (; o + 2 <= o1; o += 2) {
            int sa = esrc[o], sb = esrc[o+1];
            acc += T[(size_t)sa*64+lane] + T[(size_t)sb*64+lane];
        }
        if (o < o1) acc += T[(size_t)esrc[o]*64+lane];
        float z = fmaf(acc, dv, bcol);
        Z[(size_t)d * 64 + lane] = z;
        s1 += z; s2 += z * z;
    }
    __shared__ float sh1[256], sh2[256];
    sh1[threadIdx.x] = s1;
    sh2[threadIdx.x] = s2;
    __syncthreads();
    if (wid == 0) {
        #pragma unroll
        for (int w = 1; w < 4; ++w) { s1 += sh1[w * 64 + lane]; s2 += sh2[w * 64 + lane]; }
        atomicAdd(&S[lane], s1);
        atomicAdd(&S[64 + lane], s2);
    }
}

// F == 16: one node per wave, 4 edges per iteration (lane = 4 edge-slots x 16 cols)
__global__ __launch_bounds__(256) void k_accum16(const float* __restrict__ T, const int* __restrict__ esrc,
                                                 const int* __restrict__ off, const float* __restrict__ dinv,
                                                 const float* __restrict__ bias, float* __restrict__ Z,
                                                 float* __restrict__ S, int n) {
    const int lane = threadIdx.x & 63;
    const int wid = threadIdx.x >> 6;
    const int col = lane & 15;
    const int es  = lane >> 4;
    float s1 = 0.f, s2 = 0.f;
    const float bcol = bias[col];
    for (int d = blockIdx.x * 4 + wid; d < n; d += gridDim.x * 4) {
        int o0 = off[d], o1 = off[d + 1];
        float dv = dinv[d];
        float part = 0.f;
        for (int base = o0; base < o1; base += 4) {
            int oo = base + es;
            if (oo < o1) part += T[(size_t)esrc[oo] * 16 + col];
        }
        part += __shfl_xor(part, 16);
        part += __shfl_xor(part, 32);
        float acc = T[(size_t)d * 16 + col] + part;
        float z = fmaf(acc, dv, bcol);
        if (es == 0) {
            Z[(size_t)d * 16 + col] = z;
            s1 += z; s2 += z * z;
        }
    }
    __shared__ float sh1[256], sh2[256];
    sh1[threadIdx.x] = (es == 0) ? s1 : 0.f;
    sh2[threadIdx.x] = (es == 0) ? s2 : 0.f;
    __syncthreads();
    if (threadIdx.x < 16) {
        s1 = sh1[col]; s2 = sh2[col];
        #pragma unroll
        for (int r = 1; r < 16; ++r) { s1 += sh1[r * 16 + col]; s2 += sh2[r * 16 + col]; }
        atomicAdd(&S[col], s1);
        atomicAdd(&S[16 + col], s2);
    }
}

// ---------------- fc2 + log_softmax (fused BN+relu input) ----------------

__global__ __launch_bounds__(256) void k_fc2_lsm(const float* __restrict__ Hin, const float* __restrict__ W,
                                                 const float* __restrict__ bias, const float* __restrict__ S,
                                                 const float* __restrict__ bng, const float* __restrict__ bnb,
                                                 float inv_n, float* __restrict__ out, int n) {
    __shared__ float Ws[256];
    __shared__ float bs[16], sc[16], sf[16];
    Ws[threadIdx.x] = W[threadIdx.x];
    if (threadIdx.x < 16) {
        int c = threadIdx.x;
        bs[c] = bias[c];
        float mu = S[c] * inv_n;
        float var = S[16 + c] * inv_n - mu * mu;
        float is = rsqrtf(var + BN_EPS) * bng[c];
        sc[c] = is;
        sf[c] = bnb[c] - mu * is;
    }
    __syncthreads();
    for (int row = blockIdx.x * 256 + threadIdx.x; row < n; row += gridDim.x * 256) {
        float h[16];
        const float4* hp = (const float4*)(Hin + (size_t)row * 16);
        #pragma unroll
        for (int q = 0; q < 4; ++q) {
            float4 h4 = hp[q];
            h[q*4+0] = h4.x; h[q*4+1] = h4.y; h[q*4+2] = h4.z; h[q*4+3] = h4.w;
        }
        #pragma unroll
        for (int k = 0; k < 16; ++k) h[k] = fmaxf(fmaf(h[k], sc[k], sf[k]), 0.0f);
        float o[16];
        #pragma unroll
        for (int c = 0; c < 16; ++c) {
            float acc = bs[c];
            #pragma unroll
            for (int k = 0; k < 16; ++k) acc += h[k] * Ws[k * 16 + c];
            o[c] = acc;
        }
        float m = o[0];
        #pragma unroll
        for (int c = 1; c < 16; ++c) m = fmaxf(m, o[c]);
        float ssum = 0.f;
        #pragma unroll
        for (int c = 0; c < 16; ++c) ssum += expf(o[c] - m);
        float lse = m + logf(ssum);
        float4* op = (float4*)(out + (size_t)row * 16);
        #pragma unroll
        for (int q = 0; q < 4; ++q) {
            float4 w4;
            w4.x = o[q*4+0] - lse; w4.y = o[q*4+1] - lse;
            w4.z = o[q*4+2] - lse; w4.w = o[q*4+3] - lse;
            op[q] = w4;
        }
    }
}

// ---------------- launch ----------------

extern "C" void kernel_launch(void* const* d_in, const int* in_sizes, int n_in,
                              void* d_out, int out_size, void* d_ws, size_t ws_size,
                              hipStream_t stream) {
    const float* x      = (const float*)d_in[0];
    const int*   ei     = (const int*)d_in[1];
    const float* fc1_w  = (const float*)d_in[2];
    const float* fc1_b  = (const float*)d_in[3];
    const float* conv_w[3] = { (const float*)d_in[4],  (const float*)d_in[8],  (const float*)d_in[12] };
    const float* conv_b[3] = { (const float*)d_in[5],  (const float*)d_in[9],  (const float*)d_in[13] };
    const float* bn_g[3]   = { (const float*)d_in[6],  (const float*)d_in[10], (const float*)d_in[14] };
    const float* bn_b[3]   = { (const float*)d_in[7],  (const float*)d_in[11], (const float*)d_in[15] };
    const float* fc2_w  = (const float*)d_in[16];
    const float* fc2_b  = (const float*)d_in[17];

    const int n = in_sizes[0] / 128;
    const int e = in_sizes[1] / 2;
    const int* src = ei;
    const int* dst = ei + e;
    const float inv_n = 1.0f / (float)n;

    float* A    = (float*)d_ws;            // n*64
    float* B    = A + (size_t)n * 64;      // n*64
    float* dinv = B + (size_t)n * 64;      // n
    int*   deg  = (int*)(dinv + n);        // n  (doubles as cnt)
    int*   off  = deg + n;                 // n+1
    int*   esrc = off + n + 1;             // e
    float* stats = (float*)(esrc + e);     // 3*128
    int*   bsum = (int*)(stats + 384);     // <=512

    const int gN  = (n + 255) / 256;
    const int gE  = (e + 255) / 256;
    const int gAcc = 2048;
    const int gLin64 = (n + 63) / 64;      // TILE_R=64 kernels
    const int gLin128 = (n + 127) / 128;   // TILE_R=128 (FOUT=16)

    float* st[3] = { stats, stats + 128, stats + 256 };

    // CSR build (shared by all 3 conv layers)
    hipMemsetAsync(deg, 0, (size_t)n * sizeof(int), stream);
    hipMemsetAsync(stats, 0, 384 * sizeof(float), stream);
    k_deg_count<<<gE, 256, 0, stream>>>(dst, deg, e);
    k_dinv<<<gN, 256, 0, stream>>>(deg, dinv, n);
    k_scan1<<<gN, 256, 0, stream>>>(deg, off, bsum, n);
    k_scan2<<<1, 512, 0, stream>>>(bsum, gN);
    k_scan3<<<gN, 256, 0, stream>>>(off, bsum, deg /*cnt*/, n, e);
    k_fill<<<gE, 256, 0, stream>>>(src, dst, off, deg /*cnt*/, esrc, e);

    // fc1 + relu : A = relu(x @ W1 + b1)
    k_linear<128, 64, true, true, false, false><<<gLin64, 256, 0, stream>>>(
        x, fc1_w, fc1_b, A, nullptr, nullptr, nullptr, nullptr, 0.f, n);

    // conv0: B = (A @ W0) * dinv[row] ; A = gcn(B) (+bias, +stats0)
    k_linear<64, 64, false, false, false, true><<<gLin64, 256, 0, stream>>>(
        A, conv_w[0], nullptr, B, nullptr, nullptr, nullptr, dinv, 0.f, n);
    k_accum64<<<gAcc, 256, 0, stream>>>(B, esrc, off, dinv, conv_b[0], A, st[0], n);

    // conv1: B = (bnrelu(A) @ W1) * dinv[row] ; A = gcn(B)
    k_linear<64, 64, false, false, true, true><<<gLin64, 256, 0, stream>>>(
        A, conv_w[1], nullptr, B, st[0], bn_g[0], bn_b[0], dinv, inv_n, n);
    k_accum64<<<gAcc, 256, 0, stream>>>(B, esrc, off, dinv, conv_b[1], A, st[1], n);

    // conv2: B = (bnrelu(A) @ W2) * dinv[row] (64->16) ; A = gcn(B)
    k_linear<64, 16, false, false, true, true><<<gLin128, 256, 0, stream>>>(
        A, conv_w[2], nullptr, B, st[1], bn_g[1], bn_b[1], dinv, inv_n, n);
    k_accum16<<<gAcc, 256, 0, stream>>>(B, esrc, off, dinv, conv_b[2], A, st[2], n);

    // fc2 + log_softmax (bn+relu fused on input) -> d_out
    k_fc2_lsm<<<gLin64, 256, 0, stream>>>(A, fc2_w, fc2_b, st[2], bn_g[2], bn_b[2], inv_n, (float*)d_out, n);
}

// Round 6
// 525.556 us; speedup vs baseline: 3.1795x; 1.0396x over previous
//
#include <hip/hip_runtime.h>

#define BN_EPS 1e-5f

typedef unsigned int uint32;

__device__ __forceinline__ void fma4(float4& a, float s, const float4& w) {
    a.x = fmaf(s, w.x, a.x); a.y = fmaf(s, w.y, a.y);
    a.z = fmaf(s, w.z, a.z); a.w = fmaf(s, w.w, a.w);
}

// bf16 helpers: packed pair in one u32 (lo = even col, hi = odd col)
__device__ __forceinline__ float blo(uint32 p) { return __uint_as_float(p << 16); }
__device__ __forceinline__ float bhi(uint32 p) { return __uint_as_float(p & 0xFFFF0000u); }
__device__ __forceinline__ uint32 f2bf1(float f) {
    uint32 u = __float_as_uint(f);
    return (u + 0x7FFFu + ((u >> 16) & 1u)) >> 16;   // RNE
}
__device__ __forceinline__ uint32 packbf(float a, float b) { return f2bf1(a) | (f2bf1(b) << 16); }

// ---------------- degree ----------------

__global__ __launch_bounds__(256) void k_deg_count(const int* __restrict__ dst, int* deg, int e) {
    int i = blockIdx.x * 256 + threadIdx.x;
    if (i < e) atomicAdd(&deg[dst[i]], 1);
}

// ---------------- exclusive scan (CSR offsets) + dinv ----------------

__global__ __launch_bounds__(256) void k_scan1(const int* __restrict__ deg, int* __restrict__ off,
                                               int* __restrict__ bsum, float* __restrict__ dinv, int n) {
    __shared__ int sh[256];
    int i = blockIdx.x * 256 + threadIdx.x;
    int v = (i < n) ? deg[i] : 0;
    if (i < n) dinv[i] = rsqrtf((float)v + 1.0f);   // +1 = self-loop
    sh[threadIdx.x] = v;
    __syncthreads();
    #pragma unroll
    for (int d = 1; d < 256; d <<= 1) {
        int t = (threadIdx.x >= d) ? sh[threadIdx.x - d] : 0;
        __syncthreads();
        sh[threadIdx.x] += t;
        __syncthreads();
    }
    if (i < n) off[i] = sh[threadIdx.x] - v;
    if (threadIdx.x == 255) bsum[blockIdx.x] = sh[255];
}

__global__ __launch_bounds__(512) void k_scan2(int* bsum, int nb) {
    __shared__ int sh[512];
    int v = (threadIdx.x < nb) ? bsum[threadIdx.x] : 0;
    sh[threadIdx.x] = v;
    __syncthreads();
    #pragma unroll
    for (int d = 1; d < 512; d <<= 1) {
        int t = (threadIdx.x >= d) ? sh[threadIdx.x - d] : 0;
        __syncthreads();
        sh[threadIdx.x] += t;
        __syncthreads();
    }
    if (threadIdx.x < nb) bsum[threadIdx.x] = sh[threadIdx.x] - v;
}

__global__ __launch_bounds__(256) void k_scan3(int* __restrict__ off, const int* __restrict__ bsum,
                                               int* __restrict__ cnt, int n, int e) {
    int i = blockIdx.x * 256 + threadIdx.x;
    if (i < n) { off[i] += bsum[blockIdx.x]; cnt[i] = 0; }
    if (i == 0) off[n] = e;
}

__global__ __launch_bounds__(256) void k_fill(const int* __restrict__ src, const int* __restrict__ dst,
                                              const int* __restrict__ off, int* __restrict__ cnt,
                                              int* __restrict__ esrc, int e) {
    int i = blockIdx.x * 256 + threadIdx.x;
    if (i < e) {
        int d = dst[i];
        int slot = off[d] + atomicAdd(&cnt[d], 1);
        esrc[slot] = src[i];
    }
}

// ---------------- dense linear: X-tile and W-tile in LDS, RQx4 register sub-tile ----
// Optional epilogue: relu / dinv-scale / bf16-pack output.

template<int FIN, int FOUT, bool RELU, bool BIAS, bool BNIN, bool DSCALE, bool OBF>
__global__ __launch_bounds__(256) void k_linear(const float* __restrict__ X, const float* __restrict__ W,
                                                const float* __restrict__ bias, void* __restrict__ Yv,
                                                const float* __restrict__ S, const float* __restrict__ bng,
                                                const float* __restrict__ bnb, const float* __restrict__ dinv,
                                                float inv_n, int n) {
    constexpr int KC = 64;
    constexpr int TX = FOUT / 4;                  // col-groups (16 or 4)
    constexpr int TY = 256 / TX;                  // row-groups
    constexpr int RQ = (FOUT == 64) ? 4 : 2;      // rows per thread
    constexpr int TILE_R = TY * RQ;               // 64 or 128
    constexpr int LDX = KC + 4;
    constexpr int LDW = FOUT + 4;
    __shared__ float Xs[TILE_R][LDX];
    __shared__ float Ws[KC][LDW];
    __shared__ float scs[BNIN ? FIN : 4], sfs[BNIN ? FIN : 4];

    const int tx = threadIdx.x % TX;
    const int ty = threadIdx.x / TX;

    if (BNIN) {
        for (int c = threadIdx.x; c < FIN; c += 256) {
            float mu = S[c] * inv_n;
            float var = S[FIN + c] * inv_n - mu * mu;
            float is = rsqrtf(var + BN_EPS) * bng[c];
            scs[c] = is;
            sfs[c] = bnb[c] - mu * is;
        }
        __syncthreads();
    }

    float4 bb = make_float4(0.f, 0.f, 0.f, 0.f);
    if (BIAS) bb = *(const float4*)(bias + tx * 4);

    for (int r0 = blockIdx.x * TILE_R; r0 < n; r0 += gridDim.x * TILE_R) {
        float4 acc[RQ];
        #pragma unroll
        for (int q = 0; q < RQ; ++q) acc[q] = bb;

        for (int kc = 0; kc < FIN; kc += KC) {
            __syncthreads();
            for (int idx = threadIdx.x; idx < TILE_R * (KC / 4); idx += 256) {
                int rr = idx / (KC / 4), k4 = idx % (KC / 4);
                int row = r0 + rr;
                float4 v = make_float4(0.f, 0.f, 0.f, 0.f);
                if (row < n) v = *(const float4*)(X + (size_t)row * FIN + kc + 4 * k4);
                if (BNIN) {
                    int c = kc + 4 * k4;
                    v.x = fmaxf(fmaf(v.x, scs[c+0], sfs[c+0]), 0.f);
                    v.y = fmaxf(fmaf(v.y, scs[c+1], sfs[c+1]), 0.f);
                    v.z = fmaxf(fmaf(v.z, scs[c+2], sfs[c+2]), 0.f);
                    v.w = fmaxf(fmaf(v.w, scs[c+3], sfs[c+3]), 0.f);
                }
                *(float4*)(&Xs[rr][4 * k4]) = v;
            }
            for (int idx = threadIdx.x; idx < KC * (FOUT / 4); idx += 256) {
                int kk = idx / (FOUT / 4), c4 = idx % (FOUT / 4);
                *(float4*)(&Ws[kk][4 * c4]) = *(const float4*)(W + (size_t)(kc + kk) * FOUT + 4 * c4);
            }
            __syncthreads();

            #pragma unroll 4
            for (int k4 = 0; k4 < KC / 4; ++k4) {
                float4 w0 = *(const float4*)(&Ws[4*k4+0][tx*4]);
                float4 w1 = *(const float4*)(&Ws[4*k4+1][tx*4]);
                float4 w2 = *(const float4*)(&Ws[4*k4+2][tx*4]);
                float4 w3 = *(const float4*)(&Ws[4*k4+3][tx*4]);
                #pragma unroll
                for (int q = 0; q < RQ; ++q) {
                    float4 xv = *(const float4*)(&Xs[ty*RQ+q][4*k4]);
                    fma4(acc[q], xv.x, w0);
                    fma4(acc[q], xv.y, w1);
                    fma4(acc[q], xv.z, w2);
                    fma4(acc[q], xv.w, w3);
                }
            }
        }

        #pragma unroll
        for (int q = 0; q < RQ; ++q) {
            int row = r0 + ty * RQ + q;
            if (row < n) {
                float4 v = acc[q];
                if (RELU) {
                    v.x = fmaxf(v.x, 0.f); v.y = fmaxf(v.y, 0.f);
                    v.z = fmaxf(v.z, 0.f); v.w = fmaxf(v.w, 0.f);
                }
                if (DSCALE) {
                    float dv = dinv[row];
                    v.x *= dv; v.y *= dv; v.z *= dv; v.w *= dv;
                }
                if (OBF) {
                    uint2 pk;
                    pk.x = packbf(v.x, v.y);
                    pk.y = packbf(v.z, v.w);
                    ((uint2*)Yv)[(size_t)row * (FOUT / 4) + tx] = pk;
                } else {
                    *(float4*)((float*)Yv + (size_t)row * FOUT + tx * 4) = v;
                }
            }
        }
    }
}

// ---------------- GCN accumulate (CSR gather, bf16 messages) ----------------
// Z[d,:] = dinv[d] * ( T[d,:] + sum_{s in N(d)} T[s,:] ) + bias ; + BN partial stats
// F=64: rows are 32 u32 (128 B). Wave = 1 node; lanes 0-31 even edges, 32-63 odd.

__global__ __launch_bounds__(256) void k_accum64bf(const uint32* __restrict__ Tb, const int* __restrict__ esrc,
                                                   const int* __restrict__ off, const float* __restrict__ dinv,
                                                   const float* __restrict__ bias, float* __restrict__ Z,
                                                   float* __restrict__ S, int n) {
    const int lane = threadIdx.x & 63;
    const int wid  = threadIdx.x >> 6;
    const int lp   = lane & 31;
    const int half = lane >> 5;
    const float b0 = bias[2 * lp], b1 = bias[2 * lp + 1];
    float s1a = 0.f, s2a = 0.f, s1b = 0.f, s2b = 0.f;

    for (int d = blockIdx.x * 4 + wid; d < n; d += gridDim.x * 4) {
        int o0 = off[d], o1 = off[d + 1];
        float dv = dinv[d];
        float a0 = 0.f, a1 = 0.f;
        int o = o0 + half;
        for (; o + 6 < o1; o += 8) {          // 4 edges per half per iter (8 in flight/wave)
            int sa = esrc[o], sb = esrc[o + 2], sc = esrc[o + 4], sd = esrc[o + 6];
            uint32 pa = Tb[(size_t)sa * 32 + lp], pb = Tb[(size_t)sb * 32 + lp];
            uint32 pc = Tb[(size_t)sc * 32 + lp], pd = Tb[(size_t)sd * 32 + lp];
            a0 += (blo(pa) + blo(pb)) + (blo(pc) + blo(pd));
            a1 += (bhi(pa) + bhi(pb)) + (bhi(pc) + bhi(pd));
        }
        for (; o < o1; o += 2) {
            uint32 p = Tb[(size_t)esrc[o] * 32 + lp];
            a0 += blo(p); a1 += bhi(p);
        }
        a0 += __shfl_xor(a0, 32);
        a1 += __shfl_xor(a1, 32);
        if (half == 0) {
            uint32 p = Tb[(size_t)d * 32 + lp];   // self-loop term
            a0 += blo(p); a1 += bhi(p);
            float z0 = fmaf(a0, dv, b0), z1 = fmaf(a1, dv, b1);
            *(float2*)(Z + (size_t)d * 64 + 2 * lp) = make_float2(z0, z1);
            s1a += z0; s2a += z0 * z0; s1b += z1; s2b += z1 * z1;
        }
    }

    __shared__ float sh1[4][64], sh2[4][64];
    if (half == 0) {
        sh1[wid][2 * lp] = s1a; sh1[wid][2 * lp + 1] = s1b;
        sh2[wid][2 * lp] = s2a; sh2[wid][2 * lp + 1] = s2b;
    }
    __syncthreads();
    if (threadIdx.x < 64) {
        float t1 = 0.f, t2 = 0.f;
        #pragma unroll
        for (int w = 0; w < 4; ++w) { t1 += sh1[w][threadIdx.x]; t2 += sh2[w][threadIdx.x]; }
        atomicAdd(&S[threadIdx.x], t1);
        atomicAdd(&S[64 + threadIdx.x], t2);
    }
}

// F=16: rows are 8 u32 (32 B). Wave = 1 node, 8 edge-slots x 8 u32-lanes.
__global__ __launch_bounds__(256) void k_accum16bf(const uint32* __restrict__ Tb, const int* __restrict__ esrc,
                                                   const int* __restrict__ off, const float* __restrict__ dinv,
                                                   const float* __restrict__ bias, float* __restrict__ Z,
                                                   float* __restrict__ S, int n) {
    const int lane = threadIdx.x & 63;
    const int wid  = threadIdx.x >> 6;
    const int lp   = lane & 7;
    const int es   = lane >> 3;
    const float b0 = bias[2 * lp], b1 = bias[2 * lp + 1];
    float s1a = 0.f, s2a = 0.f, s1b = 0.f, s2b = 0.f;

    for (int d = blockIdx.x * 4 + wid; d < n; d += gridDim.x * 4) {
        int o0 = off[d], o1 = off[d + 1];
        float dv = dinv[d];
        float a0 = 0.f, a1 = 0.f;
        for (int o = o0 + es; o < o1; o += 8) {
            uint32 p = Tb[(size_t)esrc[o] * 8 + lp];
            a0 += blo(p); a1 += bhi(p);
        }
        a0 += __shfl_xor(a0, 8);  a1 += __shfl_xor(a1, 8);
        a0 += __shfl_xor(a0, 16); a1 += __shfl_xor(a1, 16);
        a0 += __shfl_xor(a0, 32); a1 += __shfl_xor(a1, 32);
        if (es == 0) {
            uint32 p = Tb[(size_t)d * 8 + lp];
            a0 += blo(p); a1 += bhi(p);
            float z0 = fmaf(a0, dv, b0), z1 = fmaf(a1, dv, b1);
            *(float2*)(Z + (size_t)d * 16 + 2 * lp) = make_float2(z0, z1);
            s1a += z0; s2a += z0 * z0; s1b += z1; s2b += z1 * z1;
        }
    }

    __shared__ float sh1[4][16], sh2[4][16];
    if (es == 0) {
        sh1[wid][2 * lp] = s1a; sh1[wid][2 * lp + 1] = s1b;
        sh2[wid][2 * lp] = s2a; sh2[wid][2 * lp + 1] = s2b;
    }
    __syncthreads();
    if (threadIdx.x < 16) {
        float t1 = 0.f, t2 = 0.f;
        #pragma unroll
        for (int w = 0; w < 4; ++w) { t1 += sh1[w][threadIdx.x]; t2 += sh2[w][threadIdx.x]; }
        atomicAdd(&S[threadIdx.x], t1);
        atomicAdd(&S[16 + threadIdx.x], t2);
    }
}

// ---------------- fc2 + log_softmax (fused BN+relu input) ----------------

__global__ __launch_bounds__(256) void k_fc2_lsm(const float* __restrict__ Hin, const float* __restrict__ W,
                                                 const float* __restrict__ bias, const float* __restrict__ S,
                                                 const float* __restrict__ bng, const float* __restrict__ bnb,
                                                 float inv_n, float* __restrict__ out, int n) {
    __shared__ float Ws[256];
    __shared__ float bs[16], sc[16], sf[16];
    Ws[threadIdx.x] = W[threadIdx.x];
    if (threadIdx.x < 16) {
        int c = threadIdx.x;
        bs[c] = bias[c];
        float mu = S[c] * inv_n;
        float var = S[16 + c] * inv_n - mu * mu;
        float is = rsqrtf(var + BN_EPS) * bng[c];
        sc[c] = is;
        sf[c] = bnb[c] - mu * is;
    }
    __syncthreads();
    for (int row = blockIdx.x * 256 + threadIdx.x; row < n; row += gridDim.x * 256) {
        float h[16];
        const float4* hp = (const float4*)(Hin + (size_t)row * 16);
        #pragma unroll
        for (int q = 0; q < 4; ++q) {
            float4 h4 = hp[q];
            h[q*4+0] = h4.x; h[q*4+1] = h4.y; h[q*4+2] = h4.z; h[q*4+3] = h4.w;
        }
        #pragma unroll
        for (int k = 0; k < 16; ++k) h[k] = fmaxf(fmaf(h[k], sc[k], sf[k]), 0.0f);
        float o[16];
        #pragma unroll
        for (int c = 0; c < 16; ++c) {
            float acc = bs[c];
            #pragma unroll
            for (int k = 0; k < 16; ++k) acc += h[k] * Ws[k * 16 + c];
            o[c] = acc;
        }
        float m = o[0];
        #pragma unroll
        for (int c = 1; c < 16; ++c) m = fmaxf(m, o[c]);
        float ssum = 0.f;
        #pragma unroll
        for (int c = 0; c < 16; ++c) ssum += expf(o[c] - m);
        float lse = m + logf(ssum);
        float4* op = (float4*)(out + (size_t)row * 16);
        #pragma unroll
        for (int q = 0; q < 4; ++q) {
            float4 w4;
            w4.x = o[q*4+0] - lse; w4.y = o[q*4+1] - lse;
            w4.z = o[q*4+2] - lse; w4.w = o[q*4+3] - lse;
            op[q] = w4;
        }
    }
}

// ---------------- launch ----------------

extern "C" void kernel_launch(void* const* d_in, const int* in_sizes, int n_in,
                              void* d_out, int out_size, void* d_ws, size_t ws_size,
                              hipStream_t stream) {
    const float* x      = (const float*)d_in[0];
    const int*   ei     = (const int*)d_in[1];
    const float* fc1_w  = (const float*)d_in[2];
    const float* fc1_b  = (const float*)d_in[3];
    const float* conv_w[3] = { (const float*)d_in[4],  (const float*)d_in[8],  (const float*)d_in[12] };
    const float* conv_b[3] = { (const float*)d_in[5],  (const float*)d_in[9],  (const float*)d_in[13] };
    const float* bn_g[3]   = { (const float*)d_in[6],  (const float*)d_in[10], (const float*)d_in[14] };
    const float* bn_b[3]   = { (const float*)d_in[7],  (const float*)d_in[11], (const float*)d_in[15] };
    const float* fc2_w  = (const float*)d_in[16];
    const float* fc2_b  = (const float*)d_in[17];

    const int n = in_sizes[0] / 128;
    const int e = in_sizes[1] / 2;
    const int* src = ei;
    const int* dst = ei + e;
    const float inv_n = 1.0f / (float)n;

    float*  A    = (float*)d_ws;            // n*64 f32
    float*  Bf   = A + (size_t)n * 64;      // n*64 region (bf16 uses half)
    uint32* Bb   = (uint32*)Bf;             // n*32 u32 (bf16 x2)
    float*  dinv = Bf + (size_t)n * 64;     // n
    int*    deg  = (int*)(dinv + n);        // n  (doubles as cnt)
    int*    off  = deg + n;                 // n+1
    int*    esrc = off + n + 1;             // e
    float*  stats = (float*)(esrc + e);     // 3*128
    int*    bsum = (int*)(stats + 384);     // <=512

    const int gN  = (n + 255) / 256;
    const int gE  = (e + 255) / 256;
    const int gAcc = 2048;
    const int gLin64 = (n + 63) / 64;
    const int gLin128 = (n + 127) / 128;

    float* st[3] = { stats, stats + 128, stats + 256 };

    // CSR build (shared by all 3 conv layers)
    hipMemsetAsync(deg, 0, (size_t)n * sizeof(int), stream);
    hipMemsetAsync(stats, 0, 384 * sizeof(float), stream);
    k_deg_count<<<gE, 256, 0, stream>>>(dst, deg, e);
    k_scan1<<<gN, 256, 0, stream>>>(deg, off, bsum, dinv, n);
    k_scan2<<<1, 512, 0, stream>>>(bsum, gN);
    k_scan3<<<gN, 256, 0, stream>>>(off, bsum, deg /*cnt*/, n, e);
    k_fill<<<gE, 256, 0, stream>>>(src, dst, off, deg /*cnt*/, esrc, e);

    // fc1 + relu : A = relu(x @ W1 + b1)   (f32 out)
    k_linear<128, 64, true, true, false, false, false><<<gLin64, 256, 0, stream>>>(
        x, fc1_w, fc1_b, A, nullptr, nullptr, nullptr, nullptr, 0.f, n);

    // conv0: Bb = bf16((A @ W0) * dinv[row]) ; A = gcn(Bb) (+bias, +stats0)
    k_linear<64, 64, false, false, false, true, true><<<gLin64, 256, 0, stream>>>(
        A, conv_w[0], nullptr, Bb, nullptr, nullptr, nullptr, dinv, 0.f, n);
    k_accum64bf<<<gAcc, 256, 0, stream>>>(Bb, esrc, off, dinv, conv_b[0], A, st[0], n);

    // conv1
    k_linear<64, 64, false, false, true, true, true><<<gLin64, 256, 0, stream>>>(
        A, conv_w[1], nullptr, Bb, st[0], bn_g[0], bn_b[0], dinv, inv_n, n);
    k_accum64bf<<<gAcc, 256, 0, stream>>>(Bb, esrc, off, dinv, conv_b[1], A, st[1], n);

    // conv2 (64 -> 16)
    k_linear<64, 16, false, false, true, true, true><<<gLin128, 256, 0, stream>>>(
        A, conv_w[2], nullptr, Bb, st[1], bn_g[1], bn_b[1], dinv, inv_n, n);
    k_accum16bf<<<gAcc, 256, 0, stream>>>(Bb, esrc, off, dinv, conv_b[2], A, st[2], n);

    // fc2 + log_softmax (bn+relu fused on input) -> d_out
    k_fc2_lsm<<<gLin64, 256, 0, stream>>>(A, fc2_w, fc2_b, st[2], bn_g[2], bn_b[2], inv_n, (float*)d_out, n);
}

// Round 7
// 498.030 us; speedup vs baseline: 3.3552x; 1.0553x over previous
//
#include <hip/hip_runtime.h>

#define BN_EPS 1e-5f

typedef unsigned int uint32;

__device__ __forceinline__ void fma4(float4& a, float s, const float4& w) {
    a.x = fmaf(s, w.x, a.x); a.y = fmaf(s, w.y, a.y);
    a.z = fmaf(s, w.z, a.z); a.w = fmaf(s, w.w, a.w);
}

// bf16 helpers: packed pair in one u32 (lo = even col, hi = odd col)
__device__ __forceinline__ float blo(uint32 p) { return __uint_as_float(p << 16); }
__device__ __forceinline__ float bhi(uint32 p) { return __uint_as_float(p & 0xFFFF0000u); }
__device__ __forceinline__ uint32 f2bf1(float f) {
    uint32 u = __float_as_uint(f);
    return (u + 0x7FFFu + ((u >> 16) & 1u)) >> 16;   // RNE
}
__device__ __forceinline__ uint32 packbf(float a, float b) { return f2bf1(a) | (f2bf1(b) << 16); }

// ---------------- degree ----------------

__global__ __launch_bounds__(256) void k_deg_count(const int* __restrict__ dst, int* deg, int e) {
    int i = blockIdx.x * 256 + threadIdx.x;
    if (i < e) atomicAdd(&deg[dst[i]], 1);
}

// ---------------- exclusive scan (CSR offsets) + dinv ----------------

__global__ __launch_bounds__(256) void k_scan1(const int* __restrict__ deg, int* __restrict__ off,
                                               int* __restrict__ bsum, float* __restrict__ dinv, int n) {
    __shared__ int sh[256];
    int i = blockIdx.x * 256 + threadIdx.x;
    int v = (i < n) ? deg[i] : 0;
    if (i < n) dinv[i] = rsqrtf((float)v + 1.0f);   // +1 = self-loop
    sh[threadIdx.x] = v;
    __syncthreads();
    #pragma unroll
    for (int d = 1; d < 256; d <<= 1) {
        int t = (threadIdx.x >= d) ? sh[threadIdx.x - d] : 0;
        __syncthreads();
        sh[threadIdx.x] += t;
        __syncthreads();
    }
    if (i < n) off[i] = sh[threadIdx.x] - v;
    if (threadIdx.x == 255) bsum[blockIdx.x] = sh[255];
}

__global__ __launch_bounds__(512) void k_scan2(int* bsum, int nb) {
    __shared__ int sh[512];
    int v = (threadIdx.x < nb) ? bsum[threadIdx.x] : 0;
    sh[threadIdx.x] = v;
    __syncthreads();
    #pragma unroll
    for (int d = 1; d < 512; d <<= 1) {
        int t = (threadIdx.x >= d) ? sh[threadIdx.x - d] : 0;
        __syncthreads();
        sh[threadIdx.x] += t;
        __syncthreads();
    }
    if (threadIdx.x < nb) bsum[threadIdx.x] = sh[threadIdx.x] - v;
}

__global__ __launch_bounds__(256) void k_scan3(int* __restrict__ off, const int* __restrict__ bsum,
                                               int* __restrict__ cnt, int n, int e) {
    int i = blockIdx.x * 256 + threadIdx.x;
    if (i < n) { off[i] += bsum[blockIdx.x]; cnt[i] = 0; }
    if (i == 0) off[n] = e;
}

__global__ __launch_bounds__(256) void k_fill(const int* __restrict__ src, const int* __restrict__ dst,
                                              const int* __restrict__ off, int* __restrict__ cnt,
                                              int* __restrict__ esrc, int e) {
    int i = blockIdx.x * 256 + threadIdx.x;
    if (i < e) {
        int d = dst[i];
        int slot = off[d] + atomicAdd(&cnt[d], 1);
        esrc[slot] = src[i];
    }
}

// ---------------- dense linear: X-tile and W-tile in LDS, RQx4 register sub-tile ----

template<int FIN, int FOUT, bool RELU, bool BIAS, bool BNIN, bool DSCALE, bool OBF>
__global__ __launch_bounds__(256) void k_linear(const float* __restrict__ X, const float* __restrict__ W,
                                                const float* __restrict__ bias, void* __restrict__ Yv,
                                                const float* __restrict__ S, const float* __restrict__ bng,
                                                const float* __restrict__ bnb, const float* __restrict__ dinv,
                                                float inv_n, int n) {
    constexpr int KC = 64;
    constexpr int TX = FOUT / 4;
    constexpr int TY = 256 / TX;
    constexpr int RQ = (FOUT == 64) ? 4 : 2;
    constexpr int TILE_R = TY * RQ;
    constexpr int LDX = KC + 4;
    constexpr int LDW = FOUT + 4;
    __shared__ float Xs[TILE_R][LDX];
    __shared__ float Ws[KC][LDW];
    __shared__ float scs[BNIN ? FIN : 4], sfs[BNIN ? FIN : 4];

    const int tx = threadIdx.x % TX;
    const int ty = threadIdx.x / TX;

    if (BNIN) {
        for (int c = threadIdx.x; c < FIN; c += 256) {
            float mu = S[c] * inv_n;
            float var = S[FIN + c] * inv_n - mu * mu;
            float is = rsqrtf(var + BN_EPS) * bng[c];
            scs[c] = is;
            sfs[c] = bnb[c] - mu * is;
        }
        __syncthreads();
    }

    float4 bb = make_float4(0.f, 0.f, 0.f, 0.f);
    if (BIAS) bb = *(const float4*)(bias + tx * 4);

    for (int r0 = blockIdx.x * TILE_R; r0 < n; r0 += gridDim.x * TILE_R) {
        float4 acc[RQ];
        #pragma unroll
        for (int q = 0; q < RQ; ++q) acc[q] = bb;

        for (int kc = 0; kc < FIN; kc += KC) {
            __syncthreads();
            for (int idx = threadIdx.x; idx < TILE_R * (KC / 4); idx += 256) {
                int rr = idx / (KC / 4), k4 = idx % (KC / 4);
                int row = r0 + rr;
                float4 v = make_float4(0.f, 0.f, 0.f, 0.f);
                if (row < n) v = *(const float4*)(X + (size_t)row * FIN + kc + 4 * k4);
                if (BNIN) {
                    int c = kc + 4 * k4;
                    v.x = fmaxf(fmaf(v.x, scs[c+0], sfs[c+0]), 0.f);
                    v.y = fmaxf(fmaf(v.y, scs[c+1], sfs[c+1]), 0.f);
                    v.z = fmaxf(fmaf(v.z, scs[c+2], sfs[c+2]), 0.f);
                    v.w = fmaxf(fmaf(v.w, scs[c+3], sfs[c+3]), 0.f);
                }
                *(float4*)(&Xs[rr][4 * k4]) = v;
            }
            for (int idx = threadIdx.x; idx < KC * (FOUT / 4); idx += 256) {
                int kk = idx / (FOUT / 4), c4 = idx % (FOUT / 4);
                *(float4*)(&Ws[kk][4 * c4]) = *(const float4*)(W + (size_t)(kc + kk) * FOUT + 4 * c4);
            }
            __syncthreads();

            #pragma unroll 4
            for (int k4 = 0; k4 < KC / 4; ++k4) {
                float4 w0 = *(const float4*)(&Ws[4*k4+0][tx*4]);
                float4 w1 = *(const float4*)(&Ws[4*k4+1][tx*4]);
                float4 w2 = *(const float4*)(&Ws[4*k4+2][tx*4]);
                float4 w3 = *(const float4*)(&Ws[4*k4+3][tx*4]);
                #pragma unroll
                for (int q = 0; q < RQ; ++q) {
                    float4 xv = *(const float4*)(&Xs[ty*RQ+q][4*k4]);
                    fma4(acc[q], xv.x, w0);
                    fma4(acc[q], xv.y, w1);
                    fma4(acc[q], xv.z, w2);
                    fma4(acc[q], xv.w, w3);
                }
            }
        }

        #pragma unroll
        for (int q = 0; q < RQ; ++q) {
            int row = r0 + ty * RQ + q;
            if (row < n) {
                float4 v = acc[q];
                if (RELU) {
                    v.x = fmaxf(v.x, 0.f); v.y = fmaxf(v.y, 0.f);
                    v.z = fmaxf(v.z, 0.f); v.w = fmaxf(v.w, 0.f);
                }
                if (DSCALE) {
                    float dv = dinv[row];
                    v.x *= dv; v.y *= dv; v.z *= dv; v.w *= dv;
                }
                if (OBF) {
                    uint2 pk;
                    pk.x = packbf(v.x, v.y);
                    pk.y = packbf(v.z, v.w);
                    ((uint2*)Yv)[(size_t)row * (FOUT / 4) + tx] = pk;
                } else {
                    *(float4*)((float*)Yv + (size_t)row * FOUT + tx * 4) = v;
                }
            }
        }
    }
}

// ---------------- GCN accumulate (CSR gather, bf16 messages, high-MLP) ----------------
// Z[d,:] = dinv[d]*(T[d,:] + sum_s T[s,:]) + bias ; + BN partial stats.
// F=64: row = 16 uint2 (128 B); lane: lp=lane&15 (uint2 idx), es=lane>>4 (slot group).
// Per 16-slot block: 4 predicated esrc loads + 4 predicated uint2 row loads (4 edges/instr).
// Two adjacent nodes per wave iteration -> up to 16 loads in flight.

__global__ __launch_bounds__(256) void k_accum64bf(const uint2* __restrict__ Tb2, const int* __restrict__ esrc,
                                                   const int* __restrict__ off, const float* __restrict__ dinv,
                                                   const float* __restrict__ bias, float* __restrict__ Z,
                                                   float* __restrict__ S, int n) {
    const int lane = threadIdx.x & 63;
    const int wid  = threadIdx.x >> 6;
    const int lp   = lane & 15;
    const int es   = lane >> 4;
    const float4 bb = *(const float4*)(bias + 4 * lp);
    float st1[4] = {0.f,0.f,0.f,0.f}, st2[4] = {0.f,0.f,0.f,0.f};
    const uint2 z2 = make_uint2(0u, 0u);

    for (int dp = blockIdx.x * 4 + wid; 2 * dp < n; dp += gridDim.x * 4) {
        const int dA = 2 * dp, dB = 2 * dp + 1;
        const int oA0 = off[dA], oA1 = off[dA + 1];
        const int oB0 = oA1;
        const int oB1 = (dB < n) ? off[dB + 1] : oA1;

        float aA0=0.f, aA1=0.f, aA2=0.f, aA3=0.f;
        float aB0=0.f, aB1=0.f, aB2=0.f, aB3=0.f;
        int bA = oA0, bB = oB0;
        while (bA < oA1 || bB < oB1) {
            if (bA < oA1) {
                int i0 = bA + 4 * es;
                int s0 = (i0     < oA1) ? esrc[i0]     : -1;
                int s1 = (i0 + 1 < oA1) ? esrc[i0 + 1] : -1;
                int s2 = (i0 + 2 < oA1) ? esrc[i0 + 2] : -1;
                int s3 = (i0 + 3 < oA1) ? esrc[i0 + 3] : -1;
                uint2 p0 = (s0 >= 0) ? Tb2[(size_t)s0 * 16 + lp] : z2;
                uint2 p1 = (s1 >= 0) ? Tb2[(size_t)s1 * 16 + lp] : z2;
                uint2 p2 = (s2 >= 0) ? Tb2[(size_t)s2 * 16 + lp] : z2;
                uint2 p3 = (s3 >= 0) ? Tb2[(size_t)s3 * 16 + lp] : z2;
                aA0 += (blo(p0.x) + blo(p1.x)) + (blo(p2.x) + blo(p3.x));
                aA1 += (bhi(p0.x) + bhi(p1.x)) + (bhi(p2.x) + bhi(p3.x));
                aA2 += (blo(p0.y) + blo(p1.y)) + (blo(p2.y) + blo(p3.y));
                aA3 += (bhi(p0.y) + bhi(p1.y)) + (bhi(p2.y) + bhi(p3.y));
            }
            if (bB < oB1) {
                int i0 = bB + 4 * es;
                int s0 = (i0     < oB1) ? esrc[i0]     : -1;
                int s1 = (i0 + 1 < oB1) ? esrc[i0 + 1] : -1;
                int s2 = (i0 + 2 < oB1) ? esrc[i0 + 2] : -1;
                int s3 = (i0 + 3 < oB1) ? esrc[i0 + 3] : -1;
                uint2 p0 = (s0 >= 0) ? Tb2[(size_t)s0 * 16 + lp] : z2;
                uint2 p1 = (s1 >= 0) ? Tb2[(size_t)s1 * 16 + lp] : z2;
                uint2 p2 = (s2 >= 0) ? Tb2[(size_t)s2 * 16 + lp] : z2;
                uint2 p3 = (s3 >= 0) ? Tb2[(size_t)s3 * 16 + lp] : z2;
                aB0 += (blo(p0.x) + blo(p1.x)) + (blo(p2.x) + blo(p3.x));
                aB1 += (bhi(p0.x) + bhi(p1.x)) + (bhi(p2.x) + bhi(p3.x));
                aB2 += (blo(p0.y) + blo(p1.y)) + (blo(p2.y) + blo(p3.y));
                aB3 += (bhi(p0.y) + bhi(p1.y)) + (bhi(p2.y) + bhi(p3.y));
            }
            bA += 16; bB += 16;
        }

        aA0 += __shfl_xor(aA0, 16); aA0 += __shfl_xor(aA0, 32);
        aA1 += __shfl_xor(aA1, 16); aA1 += __shfl_xor(aA1, 32);
        aA2 += __shfl_xor(aA2, 16); aA2 += __shfl_xor(aA2, 32);
        aA3 += __shfl_xor(aA3, 16); aA3 += __shfl_xor(aA3, 32);
        aB0 += __shfl_xor(aB0, 16); aB0 += __shfl_xor(aB0, 32);
        aB1 += __shfl_xor(aB1, 16); aB1 += __shfl_xor(aB1, 32);
        aB2 += __shfl_xor(aB2, 16); aB2 += __shfl_xor(aB2, 32);
        aB3 += __shfl_xor(aB3, 16); aB3 += __shfl_xor(aB3, 32);

        if (es == 0) {
            // node A
            uint2 ps = Tb2[(size_t)dA * 16 + lp];
            float dv = dinv[dA];
            float4 zz;
            zz.x = fmaf(aA0 + blo(ps.x), dv, bb.x);
            zz.y = fmaf(aA1 + bhi(ps.x), dv, bb.y);
            zz.z = fmaf(aA2 + blo(ps.y), dv, bb.z);
            zz.w = fmaf(aA3 + bhi(ps.y), dv, bb.w);
            *(float4*)(Z + (size_t)dA * 64 + 4 * lp) = zz;
            st1[0] += zz.x; st2[0] += zz.x * zz.x;
            st1[1] += zz.y; st2[1] += zz.y * zz.y;
            st1[2] += zz.z; st2[2] += zz.z * zz.z;
            st1[3] += zz.w; st2[3] += zz.w * zz.w;
            // node B
            if (dB < n) {
                uint2 pb = Tb2[(size_t)dB * 16 + lp];
                float dvB = dinv[dB];
                float4 zb;
                zb.x = fmaf(aB0 + blo(pb.x), dvB, bb.x);
                zb.y = fmaf(aB1 + bhi(pb.x), dvB, bb.y);
                zb.z = fmaf(aB2 + blo(pb.y), dvB, bb.z);
                zb.w = fmaf(aB3 + bhi(pb.y), dvB, bb.w);
                *(float4*)(Z + (size_t)dB * 64 + 4 * lp) = zb;
                st1[0] += zb.x; st2[0] += zb.x * zb.x;
                st1[1] += zb.y; st2[1] += zb.y * zb.y;
                st1[2] += zb.z; st2[2] += zb.z * zb.z;
                st1[3] += zb.w; st2[3] += zb.w * zb.w;
            }
        }
    }

    __shared__ float sh1[4][64], sh2[4][64];
    if (es == 0) {
        *(float4*)(&sh1[wid][4 * lp]) = make_float4(st1[0], st1[1], st1[2], st1[3]);
        *(float4*)(&sh2[wid][4 * lp]) = make_float4(st2[0], st2[1], st2[2], st2[3]);
    }
    __syncthreads();
    if (threadIdx.x < 64) {
        float t1 = 0.f, t2 = 0.f;
        #pragma unroll
        for (int w = 0; w < 4; ++w) { t1 += sh1[w][threadIdx.x]; t2 += sh2[w][threadIdx.x]; }
        atomicAdd(&S[threadIdx.x], t1);
        atomicAdd(&S[64 + threadIdx.x], t2);
    }
}

// F=16: row = 4 uint2 (32 B); lp=lane&3, es=lane>>2 (16 slot groups).
// Per 16-slot block: 1 esrc load + 1 row load (16 edges/instr). Node pairs -> 4 loads in flight.

__global__ __launch_bounds__(256) void k_accum16bf(const uint2* __restrict__ Tb2, const int* __restrict__ esrc,
                                                   const int* __restrict__ off, const float* __restrict__ dinv,
                                                   const float* __restrict__ bias, float* __restrict__ Z,
                                                   float* __restrict__ S, int n) {
    const int lane = threadIdx.x & 63;
    const int wid  = threadIdx.x >> 6;
    const int lp   = lane & 3;
    const int es   = lane >> 2;
    const float4 bb = *(const float4*)(bias + 4 * lp);
    float st1[4] = {0.f,0.f,0.f,0.f}, st2[4] = {0.f,0.f,0.f,0.f};
    const uint2 z2 = make_uint2(0u, 0u);

    for (int dp = blockIdx.x * 4 + wid; 2 * dp < n; dp += gridDim.x * 4) {
        const int dA = 2 * dp, dB = 2 * dp + 1;
        const int oA0 = off[dA], oA1 = off[dA + 1];
        const int oB0 = oA1;
        const int oB1 = (dB < n) ? off[dB + 1] : oA1;

        float aA0=0.f, aA1=0.f, aA2=0.f, aA3=0.f;
        float aB0=0.f, aB1=0.f, aB2=0.f, aB3=0.f;
        int bA = oA0, bB = oB0;
        while (bA < oA1 || bB < oB1) {
            if (bA < oA1) {
                int i0 = bA + es;
                int s0 = (i0 < oA1) ? esrc[i0] : -1;
                uint2 p0 = (s0 >= 0) ? Tb2[(size_t)s0 * 4 + lp] : z2;
                aA0 += blo(p0.x); aA1 += bhi(p0.x); aA2 += blo(p0.y); aA3 += bhi(p0.y);
            }
            if (bB < oB1) {
                int i0 = bB + es;
                int s0 = (i0 < oB1) ? esrc[i0] : -1;
                uint2 p0 = (s0 >= 0) ? Tb2[(size_t)s0 * 4 + lp] : z2;
                aB0 += blo(p0.x); aB1 += bhi(p0.x); aB2 += blo(p0.y); aB3 += bhi(p0.y);
            }
            bA += 16; bB += 16;
        }

        #pragma unroll
        for (int sh = 4; sh <= 32; sh <<= 1) {
            aA0 += __shfl_xor(aA0, sh); aA1 += __shfl_xor(aA1, sh);
            aA2 += __shfl_xor(aA2, sh); aA3 += __shfl_xor(aA3, sh);
            aB0 += __shfl_xor(aB0, sh); aB1 += __shfl_xor(aB1, sh);
            aB2 += __shfl_xor(aB2, sh); aB3 += __shfl_xor(aB3, sh);
        }

        if (es == 0) {
            uint2 ps = Tb2[(size_t)dA * 4 + lp];
            float dv = dinv[dA];
            float4 zz;
            zz.x = fmaf(aA0 + blo(ps.x), dv, bb.x);
            zz.y = fmaf(aA1 + bhi(ps.x), dv, bb.y);
            zz.z = fmaf(aA2 + blo(ps.y), dv, bb.z);
            zz.w = fmaf(aA3 + bhi(ps.y), dv, bb.w);
            *(float4*)(Z + (size_t)dA * 16 + 4 * lp) = zz;
            st1[0] += zz.x; st2[0] += zz.x * zz.x;
            st1[1] += zz.y; st2[1] += zz.y * zz.y;
            st1[2] += zz.z; st2[2] += zz.z * zz.z;
            st1[3] += zz.w; st2[3] += zz.w * zz.w;
            if (dB < n) {
                uint2 pb = Tb2[(size_t)dB * 4 + lp];
                float dvB = dinv[dB];
                float4 zb;
                zb.x = fmaf(aB0 + blo(pb.x), dvB, bb.x);
                zb.y = fmaf(aB1 + bhi(pb.x), dvB, bb.y);
                zb.z = fmaf(aB2 + blo(pb.y), dvB, bb.z);
                zb.w = fmaf(aB3 + bhi(pb.y), dvB, bb.w);
                *(float4*)(Z + (size_t)dB * 16 + 4 * lp) = zb;
                st1[0] += zb.x; st2[0] += zb.x * zb.x;
                st1[1] += zb.y; st2[1] += zb.y * zb.y;
                st1[2] += zb.z; st2[2] += zb.z * zb.z;
                st1[3] += zb.w; st2[3] += zb.w * zb.w;
            }
        }
    }

    __shared__ float sh1[4][16], sh2[4][16];
    if (es == 0) {
        *(float4*)(&sh1[wid][4 * lp]) = make_float4(st1[0], st1[1], st1[2], st1[3]);
        *(float4*)(&sh2[wid][4 * lp]) = make_float4(st2[0], st2[1], st2[2], st2[3]);
    }
    __syncthreads();
    if (threadIdx.x < 16) {
        float t1 = 0.f, t2 = 0.f;
        #pragma unroll
        for (int w = 0; w < 4; ++w) { t1 += sh1[w][threadIdx.x]; t2 += sh2[w][threadIdx.x]; }
        atomicAdd(&S[threadIdx.x], t1);
        atomicAdd(&S[16 + threadIdx.x], t2);
    }
}

// ---------------- fc2 + log_softmax (fused BN+relu input) ----------------

__global__ __launch_bounds__(256) void k_fc2_lsm(const float* __restrict__ Hin, const float* __restrict__ W,
                                                 const float* __restrict__ bias, const float* __restrict__ S,
                                                 const float* __restrict__ bng, const float* __restrict__ bnb,
                                                 float inv_n, float* __restrict__ out, int n) {
    __shared__ float Ws[256];
    __shared__ float bs[16], sc[16], sf[16];
    Ws[threadIdx.x] = W[threadIdx.x];
    if (threadIdx.x < 16) {
        int c = threadIdx.x;
        bs[c] = bias[c];
        float mu = S[c] * inv_n;
        float var = S[16 + c] * inv_n - mu * mu;
        float is = rsqrtf(var + BN_EPS) * bng[c];
        sc[c] = is;
        sf[c] = bnb[c] - mu * is;
    }
    __syncthreads();
    for (int row = blockIdx.x * 256 + threadIdx.x; row < n; row += gridDim.x * 256) {
        float h[16];
        const float4* hp = (const float4*)(Hin + (size_t)row * 16);
        #pragma unroll
        for (int q = 0; q < 4; ++q) {
            float4 h4 = hp[q];
            h[q*4+0] = h4.x; h[q*4+1] = h4.y; h[q*4+2] = h4.z; h[q*4+3] = h4.w;
        }
        #pragma unroll
        for (int k = 0; k < 16; ++k) h[k] = fmaxf(fmaf(h[k], sc[k], sf[k]), 0.0f);
        float o[16];
        #pragma unroll
        for (int c = 0; c < 16; ++c) {
            float acc = bs[c];
            #pragma unroll
            for (int k = 0; k < 16; ++k) acc += h[k] * Ws[k * 16 + c];
            o[c] = acc;
        }
        float m = o[0];
        #pragma unroll
        for (int c = 1; c < 16; ++c) m = fmaxf(m, o[c]);
        float ssum = 0.f;
        #pragma unroll
        for (int c = 0; c < 16; ++c) ssum += expf(o[c] - m);
        float lse = m + logf(ssum);
        float4* op = (float4*)(out + (size_t)row * 16);
        #pragma unroll
        for (int q = 0; q < 4; ++q) {
            float4 w4;
            w4.x = o[q*4+0] - lse; w4.y = o[q*4+1] - lse;
            w4.z = o[q*4+2] - lse; w4.w = o[q*4+3] - lse;
            op[q] = w4;
        }
    }
}

// ---------------- launch ----------------

extern "C" void kernel_launch(void* const* d_in, const int* in_sizes, int n_in,
                              void* d_out, int out_size, void* d_ws, size_t ws_size,
                              hipStream_t stream) {
    const float* x      = (const float*)d_in[0];
    const int*   ei     = (const int*)d_in[1];
    const float* fc1_w  = (const float*)d_in[2];
    const float* fc1_b  = (const float*)d_in[3];
    const float* conv_w[3] = { (const float*)d_in[4],  (const float*)d_in[8],  (const float*)d_in[12] };
    const float* conv_b[3] = { (const float*)d_in[5],  (const float*)d_in[9],  (const float*)d_in[13] };
    const float* bn_g[3]   = { (const float*)d_in[6],  (const float*)d_in[10], (const float*)d_in[14] };
    const float* bn_b[3]   = { (const float*)d_in[7],  (const float*)d_in[11], (const float*)d_in[15] };
    const float* fc2_w  = (const float*)d_in[16];
    const float* fc2_b  = (const float*)d_in[17];

    const int n = in_sizes[0] / 128;
    const int e = in_sizes[1] / 2;
    const int* src = ei;
    const int* dst = ei + e;
    const float inv_n = 1.0f / (float)n;

    float*  A    = (float*)d_ws;            // n*64 f32
    float*  Bf   = A + (size_t)n * 64;      // n*64 region (bf16 uses half)
    uint2*  Bb2  = (uint2*)Bf;
    float*  dinv = Bf + (size_t)n * 64;     // n
    int*    deg  = (int*)(dinv + n);        // n  (doubles as cnt)
    int*    off  = deg + n;                 // n+1
    int*    esrc = off + n + 1;             // e
    float*  stats = (float*)(esrc + e);     // 3*128
    int*    bsum = (int*)(stats + 384);     // <=512

    const int gN  = (n + 255) / 256;
    const int gE  = (e + 255) / 256;
    const int gAcc = 2048;
    const int gLin64 = (n + 63) / 64;
    const int gLin128 = (n + 127) / 128;

    float* st[3] = { stats, stats + 128, stats + 256 };

    // CSR build (shared by all 3 conv layers)
    hipMemsetAsync(deg, 0, (size_t)n * sizeof(int), stream);
    hipMemsetAsync(stats, 0, 384 * sizeof(float), stream);
    k_deg_count<<<gE, 256, 0, stream>>>(dst, deg, e);
    k_scan1<<<gN, 256, 0, stream>>>(deg, off, bsum, dinv, n);
    k_scan2<<<1, 512, 0, stream>>>(bsum, gN);
    k_scan3<<<gN, 256, 0, stream>>>(off, bsum, deg /*cnt*/, n, e);
    k_fill<<<gE, 256, 0, stream>>>(src, dst, off, deg /*cnt*/, esrc, e);

    // fc1 + relu : A = relu(x @ W1 + b1)   (f32 out)
    k_linear<128, 64, true, true, false, false, false><<<gLin64, 256, 0, stream>>>(
        x, fc1_w, fc1_b, A, nullptr, nullptr, nullptr, nullptr, 0.f, n);

    // conv0: Bb = bf16((A @ W0) * dinv[row]) ; A = gcn(Bb) (+bias, +stats0)
    k_linear<64, 64, false, false, false, true, true><<<gLin64, 256, 0, stream>>>(
        A, conv_w[0], nullptr, Bb2, nullptr, nullptr, nullptr, dinv, 0.f, n);
    k_accum64bf<<<gAcc, 256, 0, stream>>>(Bb2, esrc, off, dinv, conv_b[0], A, st[0], n);

    // conv1
    k_linear<64, 64, false, false, true, true, true><<<gLin64, 256, 0, stream>>>(
        A, conv_w[1], nullptr, Bb2, st[0], bn_g[0], bn_b[0], dinv, inv_n, n);
    k_accum64bf<<<gAcc, 256, 0, stream>>>(Bb2, esrc, off, dinv, conv_b[1], A, st[1], n);

    // conv2 (64 -> 16)
    k_linear<64, 16, false, false, true, true, true><<<gLin128, 256, 0, stream>>>(
        A, conv_w[2], nullptr, Bb2, st[1], bn_g[1], bn_b[1], dinv, inv_n, n);
    k_accum16bf<<<gAcc, 256, 0, stream>>>(Bb2, esrc, off, dinv, conv_b[2], A, st[2], n);

    // fc2 + log_softmax (bn+relu fused on input) -> d_out
    k_fc2_lsm<<<gLin64, 256, 0, stream>>>(A, fc2_w, fc2_b, st[2], bn_g[2], bn_b[2], inv_n, (float*)d_out, n);
}